// Round 13
// baseline (1354.008 us; speedup 1.0000x reference)
//
#include <hip/hip_runtime.h>
#include <hip/hip_bf16.h>

#define Bb 8
#define Tt 48
#define HZ 24
#define Nn 1024
#define Hh 512
#define NHEAD 8

typedef short short8 __attribute__((ext_vector_type(8)));
typedef short bf16x4 __attribute__((ext_vector_type(4)));
typedef float f32x4 __attribute__((ext_vector_type(4)));

__device__ __forceinline__ ushort f2bf(float f) {
  uint u = __builtin_bit_cast(uint, f);
  u += 0x7FFFu + ((u >> 16) & 1u);
  return (ushort)(u >> 16);
}

// K=16 bf16 MFMA: lane l holds B[k=(l>>4)*4+e][col=l&15]; stage-1 acc C-layout matches.
__device__ __forceinline__ f32x4 mfma16(bf16x4 a, bf16x4 b, f32x4 c) {
#if __has_builtin(__builtin_amdgcn_mfma_f32_16x16x16bf16_1k)
  return __builtin_amdgcn_mfma_f32_16x16x16bf16_1k(a, b, c, 0, 0, 0);
#elif __has_builtin(__builtin_amdgcn_mfma_f32_16x16x16_bf16)
  return __builtin_amdgcn_mfma_f32_16x16x16_bf16(a, b, c, 0, 0, 0);
#else
  f32x4 d;
  asm volatile("v_mfma_f32_16x16x16_bf16 %0, %1, %2, %3\n\ts_nop 7\n\ts_nop 4"
               : "=v"(d) : "v"(a), "v"(b), "v"(c));
  return d;
#endif
}

// ---- prep: repack Wv into per-lane MFMA fragment order, 8-wave layout ----
// W2[kb][w8][f=ki*4+nn][lane][e] (ushort), 512KB.
//   row = w8*64 + nn*16 + (lane&15)           (hd)
//   col = kb*64 + ki*32 + ((lane>>4)<<3) + e  (k)
__global__ void wvt2_kernel(const float* __restrict__ Wv, ushort* __restrict__ W2) {
  int t = blockIdx.x * 256 + threadIdx.x;    // [0, 262144)
  int e = t & 7;
  int lane = (t >> 3) & 63;
  int f = (t >> 9) & 7;
  int w8 = (t >> 12) & 7;
  int kb = t >> 15;
  int ki = f >> 2, nn = f & 3;
  int row = w8 * 64 + nn * 16 + (lane & 15);
  int col = kb * 64 + ki * 32 + ((lane >> 4) << 3) + e;
  W2[t] = f2bf(Wv[col * 512 + row]);
}

// ---- prep: attention weights (fp32 softmax) -> bf16 padded [B][8][32][64] ----
__global__ void attn_kernel(const float* __restrict__ xt, const float* __restrict__ tt,
                            const float* __restrict__ Wq, const float* __restrict__ bq,
                            const float* __restrict__ Wk, const float* __restrict__ bk,
                            ushort* __restrict__ attnp) {
  __shared__ float qs[24][65];
  __shared__ float ks_[48][65];
  __shared__ float sc[24][49];
  int bh = blockIdx.x;                       // 64 blocks
  int b = bh >> 3, h = bh & 7;
  int t = threadIdx.x;
  for (int e = t; e < 24 * 64; e += 256) {
    int i = e >> 6, dd = e & 63;
    float s = bq[h * 64 + dd];
    const float* r = tt + (b * 24 + i) * 64;
    #pragma unroll 8
    for (int c = 0; c < 64; ++c) s += r[c] * Wq[c * 512 + h * 64 + dd];
    qs[i][dd] = s;
  }
  for (int e = t; e < 48 * 64; e += 256) {
    int j = e >> 6, dd = e & 63;
    float s = bk[h * 64 + dd];
    const float* r = xt + (b * 48 + j) * 64;
    #pragma unroll 8
    for (int c = 0; c < 64; ++c) s += r[c] * Wk[c * 512 + h * 64 + dd];
    ks_[j][dd] = s;
  }
  __syncthreads();
  for (int e = t; e < 24 * 48; e += 256) {
    int i = e / 48, j = e - i * 48;
    float s = 0.f;
    #pragma unroll 8
    for (int dd = 0; dd < 64; ++dd) s += qs[i][dd] * ks_[j][dd];
    sc[i][j] = s * 0.125f;                   // / sqrt(64)
  }
  __syncthreads();
  if (t < 32) {
    int i = t;
    ushort* orow = attnp + ((size_t)bh * 32 + i) * 64;
    if (i < 24) {
      float mx = -1e30f;
      for (int j = 0; j < 48; ++j) mx = fmaxf(mx, sc[i][j]);
      float sum = 0.f;
      for (int j = 0; j < 48; ++j) { float e = expf(sc[i][j] - mx); sc[i][j] = e; sum += e; }
      float inv = 1.f / sum;
      for (int j = 0; j < 48; ++j) orow[j] = f2bf(sc[i][j] * inv);
      for (int j = 48; j < 64; ++j) orow[j] = 0;
    } else {
      for (int j = 0; j < 64; ++j) orow[j] = 0;
    }
  }
}

// ---- main: PERSISTENT block, cross-node double-buffered pipeline ----
// 256 blocks x 512 threads (1/CU); each block owns 32 nodes. LDS: 2 A-tiles
// (2x48KB). Per node: issue next-A loads EARLY -> kb-loop (barrier-free,
// B streamed 2-deep from L2; queue wraps across nodes since W2 repeats)
// -> register-only stage-2 -> convert+ds_write next A -> ONE barrier -> swap.
// Wave w (0..7) owns hd in [w*64, w*64+64) => head h == w.
#define A_TILE 49152

__global__ __launch_bounds__(512, 1) void main_kernel(
    const float* __restrict__ EH, const ushort* __restrict__ W2,
    const ushort* __restrict__ attnp, const float* __restrict__ bv,
    float* __restrict__ out) {
  __shared__ __align__(128) char smem[98304];
  int t = threadIdx.x;
  int lane = t & 63, w = t >> 6;             // w = head = hd64-chunk
  int rowl = lane & 15;
  int colb = (lane >> 4) << 3;               // K=32 frag k-offset (elements)
  int colb16 = (lane >> 4) << 2;             // K=16 frag k-offset (elements)
  int gn0 = blockIdx.x * 32;                 // first node (b*1024+n flat)
  int sj = t >> 7, sc4 = t & 127;            // A-stage map: rows sj+4s? no: f=s*512+t

  // hoist bv: bvr[nn], hd = w*64 + nn*16 + rowl
  float bvr[4];
  #pragma unroll
  for (int nn = 0; nn < 4; ++nn) bvr[nn] = bv[w * 64 + nn * 16 + rowl];

  // W2 panel pointers: kb stride 32768, w stride 4096, f stride 512
  #define WPTR(kbw) (W2 + (size_t)(kbw) * 32768 + w * 4096 + lane * 8)

  // ---- prologue: stage node gn0 into buf0; prime 2-deep B queue ----
  {
    int b = gn0 >> 10, n = gn0 & 1023;
    const float* ehb = EH + (((size_t)b * Tt) * Nn + n) * Hh;
    #pragma unroll
    for (int s = 0; s < 12; ++s) {
      int f = s * 512 + t;                   // 48 rows * 128 float4
      int j = f >> 7, c4 = f & 127;
      float4 v = *(const float4*)(ehb + (size_t)j * (Nn * Hh) + c4 * 4);
      uint2 p;
      p.x = (uint)f2bf(v.x) | ((uint)f2bf(v.y) << 16);
      p.y = (uint)f2bf(v.z) | ((uint)f2bf(v.w) << 16);
      int off = ((j << 10) + (c4 << 3)) ^ ((j & 7) << 4);
      *(uint2*)(smem + off) = p;
    }
  }
  short8 bq0[8], bq1[8];
  #pragma unroll
  for (int f = 0; f < 8; ++f) bq0[f] = *(const short8*)(WPTR(0) + f * 512);
  #pragma unroll
  for (int f = 0; f < 8; ++f) bq1[f] = *(const short8*)(WPTR(1) + f * 512);
  __syncthreads();

  int cur = 0;
  f32x4 acc[3][4] = {};
  for (int it = 0; it < 32; ++it) {
    int gn = gn0 + it;
    int b = gn >> 10, n = gn & 1023;
    const char* atile = smem + cur * A_TILE;

    // issue next node's A loads EARLY (consumed by ds_write after compute)
    float4 ldv[12];
    if (it < 31) {
      int gn1 = gn + 1;
      int b1 = gn1 >> 10, n1 = gn1 & 1023;
      const float* ehb = EH + (((size_t)b1 * Tt) * Nn + n1) * Hh;
      #pragma unroll
      for (int s = 0; s < 12; ++s) {
        int f = s * 512 + t;
        int j = f >> 7, c4 = f & 127;
        ldv[s] = *(const float4*)(ehb + (size_t)j * (Nn * Hh) + c4 * 4);
      }
    }

    // ---- kb loop: barrier-free; B queue wraps across nodes ----
    #pragma unroll
    for (int kb = 0; kb < 8; ++kb) {
      short8 bn[8];
      {
        const ushort* wp = WPTR((kb + 2) & 7);
        #pragma unroll
        for (int f = 0; f < 8; ++f) bn[f] = *(const short8*)(wp + f * 512);
      }
      short8 af[2][3];
      #pragma unroll
      for (int ki = 0; ki < 2; ++ki) {
        int kc = kb * 64 + ki * 32 + colb;
        #pragma unroll
        for (int m = 0; m < 3; ++m) {
          int j = m * 16 + rowl;
          int off = ((j << 10) + (kc << 1)) ^ ((j & 7) << 4);
          af[ki][m] = *(const short8*)(atile + off);
        }
      }
      __builtin_amdgcn_s_setprio(1);
      #pragma unroll
      for (int m = 0; m < 3; ++m)
        #pragma unroll
        for (int nn = 0; nn < 4; ++nn)
          acc[m][nn] = __builtin_amdgcn_mfma_f32_16x16x32_bf16(af[0][m], bq0[nn], acc[m][nn], 0, 0, 0);
      #pragma unroll
      for (int m = 0; m < 3; ++m)
        #pragma unroll
        for (int nn = 0; nn < 4; ++nn)
          acc[m][nn] = __builtin_amdgcn_mfma_f32_16x16x32_bf16(af[1][m], bq0[4 + nn], acc[m][nn], 0, 0, 0);
      __builtin_amdgcn_s_setprio(0);
      #pragma unroll
      for (int f = 0; f < 8; ++f) { bq0[f] = bq1[f]; bq1[f] = bn[f]; }
    }

    // ---- stage 2 (register-only): X[i,hd] = sum_j attn[w,i,j] * V[j,hd] ----
    {
      const ushort* arow = attnp + ((size_t)(b * 8 + w) * 32) * 64;
      f32x4 x[2][4] = {};
      #pragma unroll
      for (int m = 0; m < 3; ++m) {
        bf16x4 pa[2];
        #pragma unroll
        for (int itl = 0; itl < 2; ++itl)
          pa[itl] = *(const bf16x4*)(arow + (itl * 16 + rowl) * 64 + m * 16 + colb16);
        #pragma unroll
        for (int nn = 0; nn < 4; ++nn) {
          bf16x4 vbq;
          vbq[0] = (short)f2bf(acc[m][nn][0]);
          vbq[1] = (short)f2bf(acc[m][nn][1]);
          vbq[2] = (short)f2bf(acc[m][nn][2]);
          vbq[3] = (short)f2bf(acc[m][nn][3]);
          x[0][nn] = mfma16(pa[0], vbq, x[0][nn]);
          x[1][nn] = mfma16(pa[1], vbq, x[1][nn]);
        }
      }
      #pragma unroll
      for (int itl = 0; itl < 2; ++itl) {
        int ib = itl * 16 + ((lane >> 4) << 2);
        #pragma unroll
        for (int nn = 0; nn < 4; ++nn) {
          int hd = w * 64 + nn * 16 + rowl;
          #pragma unroll
          for (int r = 0; r < 4; ++r) {
            int i = ib + r;
            if (i < 24)
              out[(((size_t)b * HZ + i) * Nn + n) * Hh + hd] = x[itl][nn][r] + bvr[nn];
          }
        }
      }
      #pragma unroll
      for (int m = 0; m < 3; ++m)
        #pragma unroll
        for (int nn = 0; nn < 4; ++nn)
          acc[m][nn] = f32x4{0.f, 0.f, 0.f, 0.f};
    }

    // ---- write next node's A into the other buffer, then swap ----
    if (it < 31) {
      char* dst = smem + (cur ^ 1) * A_TILE;
      #pragma unroll
      for (int s = 0; s < 12; ++s) {
        int f = s * 512 + t;
        int j = f >> 7, c4 = f & 127;
        uint2 p;
        p.x = (uint)f2bf(ldv[s].x) | ((uint)f2bf(ldv[s].y) << 16);
        p.y = (uint)f2bf(ldv[s].z) | ((uint)f2bf(ldv[s].w) << 16);
        int off = ((j << 10) + (c4 << 3)) ^ ((j & 7) << 4);
        *(uint2*)(dst + off) = p;
      }
    }
    __syncthreads();
    cur ^= 1;
  }
}

extern "C" void kernel_launch(void* const* d_in, const int* in_sizes, int n_in,
                              void* d_out, int out_size, void* d_ws, size_t ws_size,
                              hipStream_t stream) {
  (void)in_sizes; (void)n_in; (void)out_size; (void)ws_size;
  const float* EH = (const float*)d_in[0];
  const float* xt = (const float*)d_in[1];
  const float* tt = (const float*)d_in[2];
  const float* Wq = (const float*)d_in[3];
  const float* bq = (const float*)d_in[4];
  const float* Wk = (const float*)d_in[5];
  const float* bk = (const float*)d_in[6];
  const float* Wv = (const float*)d_in[7];
  const float* bv = (const float*)d_in[8];
  float* out = (float*)d_out;
  ushort* W2 = (ushort*)d_ws;                                    // 512 KB
  ushort* attnp = (ushort*)((char*)d_ws + 512 * 1024);           // 256 KB

  wvt2_kernel<<<1024, 256, 0, stream>>>(Wv, W2);
  attn_kernel<<<64, 256, 0, stream>>>(xt, tt, Wq, bq, Wk, bk, attnp);
  main_kernel<<<256, 512, 0, stream>>>(EH, W2, attnp, bv, out);
}